// Round 6
// baseline (130.158 us; speedup 1.0000x reference)
//
#include <hip/hip_runtime.h>

#define N_NODES 100000
#define N_EDGES 1250000
#define D_FEAT 64

#define NB_SHIFT 7
#define NODES_PER_B 128
#define N_BUCKETS ((N_NODES + NODES_PER_B - 1) / NODES_PER_B)   // 782
#define TROW (N_BUCKETS + 1)                                     // 783
#define NB_PAD 1024
#define MAX_BUCKET_EDGES 2048        // mean 1598, sigma 40 -> 11 sigma headroom
#define SRC_BITS 17
#define SRC_MASK ((1u << SRC_BITS) - 1u)

#define BLK1 512                     // k1 block (8 waves; ~22 KB LDS -> 2+ blocks/CU)
#define CH 2496                      // chunk size
#define NCH ((N_EDGES + CH - 1) / CH)        // 501
#define NCHP 512                             // padded row stride of transposed table
#define EPT 5                                // ceil(CH / BLK1) edges per thread

#define NR 4                         // source-id ranges (L2 slices)
#define RANGE_SZ 25000u              // 25000 nodes * 128 B = 3.2 MB < 4 MB L2
#define NKEY (NODES_PER_B * NR)      // 512 CSR bins per bucket

typedef float f32x4 __attribute__((ext_vector_type(4)));   // nontemporal-safe

// ---------------- fallback: edge-parallel fp32 atomics ----------------------
__global__ __launch_bounds__(256) void lgconv_scatter(
    const float* __restrict__ x, const int* __restrict__ src,
    const int* __restrict__ dst, float* __restrict__ out) {
    int tid  = blockIdx.x * blockDim.x + threadIdx.x;
    int edge = tid >> 4;
    int f4   = (tid & 15) << 2;
    if (edge >= N_EDGES) return;
    int s = src[edge], d = dst[edge];
    const float4 v = *reinterpret_cast<const float4*>(x + (size_t)s * D_FEAT + f4);
    float* o = out + (size_t)d * D_FEAT + f4;
    unsafeAtomicAdd(o + 0, v.x); unsafeAtomicAdd(o + 1, v.y);
    unsafeAtomicAdd(o + 2, v.z); unsafeAtomicAdd(o + 3, v.w);
}

// ---------------- bf16 helpers ----------------------------------------------
__device__ __forceinline__ unsigned short f2bf(float f) {
    unsigned int u = __float_as_uint(f);
    return (unsigned short)((u + 0x7FFFu + ((u >> 16) & 1u)) >> 16);
}
__device__ __forceinline__ float bflo(unsigned int p) {
    return __uint_as_float(p << 16);
}
__device__ __forceinline__ float bfhi(unsigned int p) {
    return __uint_as_float(p & 0xFFFF0000u);
}

// ---------------- wave-level inclusive scan (wave64, no barriers) -----------
__device__ __forceinline__ int wscan_incl(int v) {
    const int lane = threadIdx.x & 63;
#pragma unroll
    for (int off = 1; off < 64; off <<= 1) {
        int u = __shfl_up(v, off, 64);
        if (lane >= off) v += u;
    }
    return v;
}

// ---------------- k1: conv x->bf16 (row-major) + per-chunk counting sort ----
// 512 threads, ~22 KB LDS -> 2+ co-resident blocks/CU so barrier phases of
// one block hide under another's memory phases. Edges read from HBM once
// (dst/src cached in statically-unrolled register arrays across phases).
template <bool CONV>
__global__ __launch_bounds__(BLK1, 4) void k1_sort(
    const float* __restrict__ x, unsigned short* __restrict__ xb,
    const int* __restrict__ src, const int* __restrict__ dst,
    unsigned int* __restrict__ bins, unsigned short* __restrict__ tableT) {
    __shared__ int hist[NB_PAD];
    __shared__ int scanBase[NB_PAD];
    __shared__ int cur[NB_PAD];
    __shared__ int wsum[BLK1 / 64];
    __shared__ unsigned int stage[CH];
    const int t    = threadIdx.x;
    const int c    = blockIdx.x;
    const int base = c * CH;
    const int cnt  = min(CH, N_EDGES - base);
    const int lane = t & 63;
    const int wid  = t >> 6;

    if (CONV) {   // fused fp32 -> bf16 conversion (row-major 128 B rows)
        const int F4 = N_NODES * D_FEAT / 4;
        for (int i = c * BLK1 + t; i < F4; i += NCH * BLK1) {
            float4 v = reinterpret_cast<const float4*>(x)[i];
            ushort4 o;
            o.x = f2bf(v.x); o.y = f2bf(v.y); o.z = f2bf(v.z); o.w = f2bf(v.w);
            reinterpret_cast<ushort4*>(xb)[i] = o;
        }
    }

    hist[t] = 0; hist[t + BLK1] = 0;
    cur[t]  = 0; cur[t + BLK1]  = 0;
    __syncthreads();

    // load edges ONCE into registers (static unroll -> stays in VGPRs)
    int rd[EPT], rs[EPT];
#pragma unroll
    for (int r = 0; r < EPT; ++r) {
        int i = t + r * BLK1;
        if (i < cnt) {
            rd[r] = dst[base + i];
            rs[r] = src[base + i];
            atomicAdd(&hist[rd[r] >> NB_SHIFT], 1);
        } else {
            rd[r] = -1;
        }
    }
    __syncthreads();

    // pair-per-thread scan over 1024 bins (512 threads, 8 waves)
    int v0 = hist[2 * t], v1 = hist[2 * t + 1];
    int pv = v0 + v1;
    int s  = wscan_incl(pv);
    if (lane == 63) wsum[wid] = s;               // 8 wave totals
    __syncthreads();
    if (t < BLK1 / 64) {
        int w  = wsum[t];
        wsum[t] = wscan_incl(w);
    }
    __syncthreads();
    int incl = s + (wid ? wsum[wid - 1] : 0);
    int eb   = incl - pv;
    scanBase[2 * t]     = eb;
    scanBase[2 * t + 1] = eb + v0;
    __syncthreads();

    // transposed u16 table: row = bucket, col = chunk (k2 reads coalesced)
    for (int i = t; i < TROW; i += BLK1)
        tableT[(size_t)i * NCHP + c] = (unsigned short)scanBase[i];

    // scatter from registers into sorted LDS stage
#pragma unroll
    for (int r = 0; r < EPT; ++r) {
        if (rd[r] >= 0) {
            int b = rd[r] >> NB_SHIFT;
            unsigned int packed =
                ((unsigned int)(rd[r] & (NODES_PER_B - 1)) << SRC_BITS)
                | (unsigned int)rs[r];
            int pos = scanBase[b] + atomicAdd(&cur[b], 1);
            stage[pos] = packed;
        }
    }
    __syncthreads();
    for (int i = t; i < cnt; i += BLK1) bins[base + i] = stage[i];
}

// ---------------- k2: bucket CSR sub-binned by source range -----------------
// 782 blocks, ~4/CU -> whole grid co-resident. Phase D makes NR=4 lockstep
// passes; pass r touches only source rows in [r*25000,(r+1)*25000) -> 3.2 MB
// slice resident in per-XCD L2. Rows stay whole (128 B, 2 lines/edge) and
// accumulators persist across passes (no extra reduces/stores).
template <bool BF>
__global__ __launch_bounds__(512) void k2_accum(
    const float* __restrict__ x, const unsigned short* __restrict__ xb,
    const unsigned int* __restrict__ bins, const unsigned short* __restrict__ tableT,
    float* __restrict__ out) {
    __shared__ int            startA[512];
    __shared__ unsigned short lenA[512];
    __shared__ int            destB[512];
    __shared__ unsigned int   raw[MAX_BUCKET_EDGES];
    __shared__ unsigned int   srcs[MAX_BUCKET_EDGES];
    __shared__ int cntArr[NKEY];
    __shared__ int nodeOff[NKEY + 1];
    __shared__ int curN[NKEY];
    __shared__ int wsum[8];
    const int t    = threadIdx.x;
    const int b    = blockIdx.x;
    const int lane = t & 63;
    const int wid  = t >> 6;

    // phase A: per-chunk fragment start/len (coalesced u16 row reads) + scan
    int st = 0, len = 0;
    if (t < NCH) {
        st  = __builtin_nontemporal_load(tableT + (size_t)b * NCHP + t);
        len = (int)__builtin_nontemporal_load(tableT + (size_t)(b + 1) * NCHP + t) - st;
    }
    startA[t] = st;
    lenA[t]   = (unsigned short)len;
    cntArr[t] = 0;                               // all 512 keys
    int s = wscan_incl(len);
    if (lane == 63) wsum[wid] = s;               // 8 wave totals
    __syncthreads();
    if (t < 8) {
        int w  = wsum[t];
        wsum[t] = wscan_incl(w);
    }
    __syncthreads();
    int incl = s + (wid ? wsum[wid - 1] : 0);
    destB[t] = incl - len;
    int cntTot = wsum[7];                        // bucket edge total
    if (cntTot > MAX_BUCKET_EDGES) cntTot = MAX_BUCKET_EDGES;
    __syncthreads();                             // destB visible to all waves

    // phase B: gather fragments into raw[] (4 lanes/fragment, nontemporal;
    // fragments average ~3.2 edges at NCH=501)
    {
        const int cj = t >> 2;                   // 128 fragments per sweep
        const int jj = t & 3;
        for (int c0 = 0; c0 < NCH; c0 += 128) {
            int c = c0 + cj;
            if (c < NCH) {
                int l = lenA[c], s0 = startA[c], db = destB[c];
                const unsigned int* p = bins + (size_t)c * CH + s0;
                for (int q = jj; q < l; q += 4)
                    raw[db + q] = __builtin_nontemporal_load(p + q);
            }
        }
    }
    __syncthreads();

    // phase C: 512-bin CSR keyed by (local_node, src_range)
    for (int i = t; i < cntTot; i += 512) {
        unsigned int p = raw[i];
        int key = ((p >> SRC_BITS) << 2) | ((p & SRC_MASK) / RANGE_SZ);
        atomicAdd(&cntArr[key], 1);
    }
    __syncthreads();
    int v2 = cntArr[t];
    int s2 = wscan_incl(v2);
    if (lane == 63) wsum[wid] = s2;
    __syncthreads();
    if (t < 8) {
        int w  = wsum[t];
        wsum[t] = wscan_incl(w);
    }
    __syncthreads();
    int excl = s2 + (wid ? wsum[wid - 1] : 0) - v2;
    nodeOff[t] = excl;
    curN[t]    = excl;
    if (t == 0) nodeOff[NKEY] = cntTot;
    __syncthreads();
    for (int i = t; i < cntTot; i += 512) {
        unsigned int p = raw[i];
        int key = ((p >> SRC_BITS) << 2) | ((p & SRC_MASK) / RANGE_SZ);
        int pos = atomicAdd(&curN[key], 1);
        srcs[pos] = p & SRC_MASK;
    }
    __syncthreads();

    // phase D: range-sliced gather-sum, persistent accumulators
    if (BF) {
        const int f0  = (t & 7) << 3;            // 16 B (8 bf16) per lane
        const int sub = t >> 3;                  // node slot 0..63
        float a0=0,a1=0,a2=0,a3=0,a4=0,a5=0,a6=0,a7=0;   // node sub
        float b0=0,b1=0,b2=0,b3=0,b4=0,b5=0,b6=0,b7=0;   // node 64+sub
        for (int r = 0; r < NR; ++r) {
            {   // g = 0
                int idx = (sub << 2) | r;
                int k = nodeOff[idx], end = nodeOff[idx + 1];
                for (; k + 1 < end; k += 2) {
                    const uint4 u0 = *reinterpret_cast<const uint4*>(
                        xb + (size_t)srcs[k] * D_FEAT + f0);
                    const uint4 u1 = *reinterpret_cast<const uint4*>(
                        xb + (size_t)srcs[k + 1] * D_FEAT + f0);
                    a0 += bflo(u0.x) + bflo(u1.x);
                    a1 += bfhi(u0.x) + bfhi(u1.x);
                    a2 += bflo(u0.y) + bflo(u1.y);
                    a3 += bfhi(u0.y) + bfhi(u1.y);
                    a4 += bflo(u0.z) + bflo(u1.z);
                    a5 += bfhi(u0.z) + bfhi(u1.z);
                    a6 += bflo(u0.w) + bflo(u1.w);
                    a7 += bfhi(u0.w) + bfhi(u1.w);
                }
                if (k < end) {
                    const uint4 u = *reinterpret_cast<const uint4*>(
                        xb + (size_t)srcs[k] * D_FEAT + f0);
                    a0 += bflo(u.x); a1 += bfhi(u.x);
                    a2 += bflo(u.y); a3 += bfhi(u.y);
                    a4 += bflo(u.z); a5 += bfhi(u.z);
                    a6 += bflo(u.w); a7 += bfhi(u.w);
                }
            }
            {   // g = 1
                int idx = ((64 + sub) << 2) | r;
                int k = nodeOff[idx], end = nodeOff[idx + 1];
                for (; k + 1 < end; k += 2) {
                    const uint4 u0 = *reinterpret_cast<const uint4*>(
                        xb + (size_t)srcs[k] * D_FEAT + f0);
                    const uint4 u1 = *reinterpret_cast<const uint4*>(
                        xb + (size_t)srcs[k + 1] * D_FEAT + f0);
                    b0 += bflo(u0.x) + bflo(u1.x);
                    b1 += bfhi(u0.x) + bfhi(u1.x);
                    b2 += bflo(u0.y) + bflo(u1.y);
                    b3 += bfhi(u0.y) + bfhi(u1.y);
                    b4 += bflo(u0.z) + bflo(u1.z);
                    b5 += bfhi(u0.z) + bfhi(u1.z);
                    b6 += bflo(u0.w) + bflo(u1.w);
                    b7 += bfhi(u0.w) + bfhi(u1.w);
                }
                if (k < end) {
                    const uint4 u = *reinterpret_cast<const uint4*>(
                        xb + (size_t)srcs[k] * D_FEAT + f0);
                    b0 += bflo(u.x); b1 += bfhi(u.x);
                    b2 += bflo(u.y); b3 += bfhi(u.y);
                    b4 += bflo(u.z); b5 += bfhi(u.z);
                    b6 += bflo(u.w); b7 += bfhi(u.w);
                }
            }
            __syncthreads();                     // keep ranges in lockstep
        }
        {
            int node = b * NODES_PER_B + sub;
            if (node < N_NODES) {
                float* op = out + (size_t)node * D_FEAT + f0;
                f32x4 w0 = {a0, a1, a2, a3};
                f32x4 w1 = {a4, a5, a6, a7};
                __builtin_nontemporal_store(w0, reinterpret_cast<f32x4*>(op));
                __builtin_nontemporal_store(w1, reinterpret_cast<f32x4*>(op + 4));
            }
            node = b * NODES_PER_B + 64 + sub;
            if (node < N_NODES) {
                float* op = out + (size_t)node * D_FEAT + f0;
                f32x4 w0 = {b0, b1, b2, b3};
                f32x4 w1 = {b4, b5, b6, b7};
                __builtin_nontemporal_store(w0, reinterpret_cast<f32x4*>(op));
                __builtin_nontemporal_store(w1, reinterpret_cast<f32x4*>(op + 4));
            }
        }
    } else {
        // fp32: 16 lanes/node, float4 per lane (x in original layout)
        int lane4 = (t & 15) << 2;
        for (int g = 0; g < NODES_PER_B / 32; ++g) {       // 4 passes
            int local = g * 32 + (t >> 4);
            int node  = b * NODES_PER_B + local;
            int beg = nodeOff[local << 2], end = nodeOff[(local << 2) + 4];
            float4 acc = make_float4(0.f, 0.f, 0.f, 0.f);
            int k = beg;
            for (; k + 1 < end; k += 2) {
                unsigned int i0 = srcs[k], i1 = srcs[k + 1];
                const float4 a = *reinterpret_cast<const float4*>(x + (size_t)i0 * D_FEAT + lane4);
                const float4 c = *reinterpret_cast<const float4*>(x + (size_t)i1 * D_FEAT + lane4);
                acc.x += a.x + c.x; acc.y += a.y + c.y;
                acc.z += a.z + c.z; acc.w += a.w + c.w;
            }
            if (k < end) {
                unsigned int i0 = srcs[k];
                const float4 a = *reinterpret_cast<const float4*>(x + (size_t)i0 * D_FEAT + lane4);
                acc.x += a.x; acc.y += a.y; acc.z += a.z; acc.w += a.w;
            }
            if (node < N_NODES)
                *reinterpret_cast<float4*>(out + (size_t)node * D_FEAT + lane4) = acc;
        }
    }
}

extern "C" void kernel_launch(void* const* d_in, const int* in_sizes, int n_in,
                              void* d_out, int out_size, void* d_ws, size_t ws_size,
                              hipStream_t stream) {
    const float* x   = (const float*)d_in[1];
    const int*   ei  = (const int*)d_in[2];
    const int*   src = ei;
    const int*   dst = ei + N_EDGES;
    float*       out = (float*)d_out;

    const size_t tabBytes = (size_t)TROW * NCHP * sizeof(unsigned short); // ~800 KB
    const size_t binBytes = (size_t)N_EDGES * sizeof(unsigned int);       // 5 MB
    const size_t xbOff    = (binBytes + tabBytes + 15) & ~(size_t)15;
    const size_t needA    = xbOff + (size_t)N_NODES * D_FEAT * sizeof(unsigned short); // ~18.6 MB
    const size_t needB    = binBytes + tabBytes;                                        // ~5.8 MB

    if (ws_size >= needA) {
        unsigned int*   bins   = (unsigned int*)d_ws;
        unsigned short* tableT = (unsigned short*)((char*)d_ws + binBytes);
        unsigned short* xb     = (unsigned short*)((char*)d_ws + xbOff);
        k1_sort<true><<<NCH, BLK1, 0, stream>>>(x, xb, src, dst, bins, tableT);
        k2_accum<true><<<N_BUCKETS, 512, 0, stream>>>(x, xb, bins, tableT, out);
    } else if (ws_size >= needB) {
        unsigned int*   bins   = (unsigned int*)d_ws;
        unsigned short* tableT = (unsigned short*)((char*)d_ws + binBytes);
        k1_sort<false><<<NCH, BLK1, 0, stream>>>(x, nullptr, src, dst, bins, tableT);
        k2_accum<false><<<N_BUCKETS, 512, 0, stream>>>(x, nullptr, bins, tableT, out);
    } else {
        (void)hipMemsetAsync(out, 0, (size_t)out_size * sizeof(float), stream);
        const int total = N_EDGES * 16;
        lgconv_scatter<<<(total + 255) / 256, 256, 0, stream>>>(x, src, dst, out);
    }
}

// Round 7
// 123.022 us; speedup vs baseline: 1.0580x; 1.0580x over previous
//
#include <hip/hip_runtime.h>

#define N_NODES 100000
#define N_EDGES 1250000
#define D_FEAT 64

#define NB_SHIFT 7
#define NODES_PER_B 128
#define N_BUCKETS ((N_NODES + NODES_PER_B - 1) / NODES_PER_B)   // 782
#define TROW (N_BUCKETS + 1)                                     // 783
#define NB_PAD 1024
#define MAX_BUCKET_EDGES 2048        // mean 1598, sigma 40 -> 11 sigma headroom
#define SRC_BITS 17
#define SRC_MASK ((1u << SRC_BITS) - 1u)

#define CH 4992                      // NCH=251 blocks -> all CUs busy in k1
#define NCH ((N_EDGES + CH - 1) / CH)        // 251
#define NCHP 256                             // padded row stride of transposed table
#define EPT 5                                // ceil(CH / 1024) edges per thread

#define NR 4                         // source-id ranges (L2 slices)
#define RANGE_SZ 25000u              // 25000 nodes * 128 B = 3.2 MB < 4 MB L2
#define NKEY (NODES_PER_B * NR)      // 512 CSR bins per bucket

typedef float f32x4 __attribute__((ext_vector_type(4)));   // nontemporal-safe

// ---------------- fallback: edge-parallel fp32 atomics ----------------------
__global__ __launch_bounds__(256) void lgconv_scatter(
    const float* __restrict__ x, const int* __restrict__ src,
    const int* __restrict__ dst, float* __restrict__ out) {
    int tid  = blockIdx.x * blockDim.x + threadIdx.x;
    int edge = tid >> 4;
    int f4   = (tid & 15) << 2;
    if (edge >= N_EDGES) return;
    int s = src[edge], d = dst[edge];
    const float4 v = *reinterpret_cast<const float4*>(x + (size_t)s * D_FEAT + f4);
    float* o = out + (size_t)d * D_FEAT + f4;
    unsafeAtomicAdd(o + 0, v.x); unsafeAtomicAdd(o + 1, v.y);
    unsafeAtomicAdd(o + 2, v.z); unsafeAtomicAdd(o + 3, v.w);
}

// ---------------- bf16 helpers ----------------------------------------------
__device__ __forceinline__ unsigned short f2bf(float f) {
    unsigned int u = __float_as_uint(f);
    return (unsigned short)((u + 0x7FFFu + ((u >> 16) & 1u)) >> 16);
}
__device__ __forceinline__ float bflo(unsigned int p) {
    return __uint_as_float(p << 16);
}
__device__ __forceinline__ float bfhi(unsigned int p) {
    return __uint_as_float(p & 0xFFFF0000u);
}

// ---------------- wave-level inclusive scan (wave64, no barriers) -----------
__device__ __forceinline__ int wscan_incl(int v) {
    const int lane = threadIdx.x & 63;
#pragma unroll
    for (int off = 1; off < 64; off <<= 1) {
        int u = __shfl_up(v, off, 64);
        if (lane >= off) v += u;
    }
    return v;
}

// ---------------- k1: conv x->bf16 (row-major) + per-chunk counting sort ----
// Round-5 structure (1024 threads, NCH=251). Edges read from HBM exactly once:
// dst/src cached in statically-unrolled register arrays across hist->scatter.
template <bool CONV>
__global__ __launch_bounds__(1024) void k1_sort(
    const float* __restrict__ x, unsigned short* __restrict__ xb,
    const int* __restrict__ src, const int* __restrict__ dst,
    unsigned int* __restrict__ bins, unsigned short* __restrict__ tableT) {
    __shared__ int hist[NB_PAD];
    __shared__ int scanBase[NB_PAD];
    __shared__ int cur[NB_PAD];
    __shared__ int wsum[16];
    __shared__ unsigned int stage[CH];
    const int t    = threadIdx.x;
    const int c    = blockIdx.x;
    const int base = c * CH;
    const int cnt  = min(CH, N_EDGES - base);
    const int lane = t & 63;
    const int wid  = t >> 6;

    if (CONV) {   // fused fp32 -> bf16 conversion (row-major 128 B rows)
        const int F4 = N_NODES * D_FEAT / 4;
        for (int i = c * 1024 + t; i < F4; i += NCH * 1024) {
            float4 v = reinterpret_cast<const float4*>(x)[i];
            ushort4 o;
            o.x = f2bf(v.x); o.y = f2bf(v.y); o.z = f2bf(v.z); o.w = f2bf(v.w);
            reinterpret_cast<ushort4*>(xb)[i] = o;
        }
    }

    hist[t] = 0; cur[t] = 0;
    __syncthreads();

    // load edges ONCE into registers (static unroll -> stays in VGPRs)
    int rd[EPT], rs[EPT];
#pragma unroll
    for (int r = 0; r < EPT; ++r) {
        int i = t + r * 1024;
        if (i < cnt) {
            rd[r] = dst[base + i];
            rs[r] = src[base + i];
            atomicAdd(&hist[rd[r] >> NB_SHIFT], 1);
        } else {
            rd[r] = -1;
        }
    }
    __syncthreads();

    int v = hist[t];
    int s = wscan_incl(v);                       // inclusive within wave
    if (lane == 63) wsum[wid] = s;               // 16 wave totals
    __syncthreads();
    if (t < 16) {
        int w  = wsum[t];
        wsum[t] = wscan_incl(w);
    }
    __syncthreads();
    int incl = s + (wid ? wsum[wid - 1] : 0);
    scanBase[t] = incl - v;                      // exclusive scan
    __syncthreads();

    // transposed u16 table: row = bucket, col = chunk (k2 reads coalesced)
    if (t < TROW) tableT[(size_t)t * NCHP + c] = (unsigned short)scanBase[t];

    // scatter from registers into sorted LDS stage
#pragma unroll
    for (int r = 0; r < EPT; ++r) {
        if (rd[r] >= 0) {
            int b = rd[r] >> NB_SHIFT;
            unsigned int packed =
                ((unsigned int)(rd[r] & (NODES_PER_B - 1)) << SRC_BITS)
                | (unsigned int)rs[r];
            int pos = scanBase[b] + atomicAdd(&cur[b], 1);
            stage[pos] = packed;
        }
    }
    __syncthreads();
    for (int i = t; i < cnt; i += 1024) bins[base + i] = stage[i];
}

// ---------------- k2: bucket CSR sub-binned by source range -----------------
// 782 blocks, ~4/CU -> whole grid co-resident. Phase D makes NR=4 lockstep
// passes; pass r touches only source rows in [r*25000,(r+1)*25000) -> 3.2 MB
// slice resident in per-XCD L2. Rows stay whole (128 B, 2 lines/edge) and
// accumulators persist across passes (no extra reduces/stores).
template <bool BF>
__global__ __launch_bounds__(512) void k2_accum(
    const float* __restrict__ x, const unsigned short* __restrict__ xb,
    const unsigned int* __restrict__ bins, const unsigned short* __restrict__ tableT,
    float* __restrict__ out) {
    __shared__ int            startA[512];
    __shared__ unsigned short lenA[512];
    __shared__ int            destB[512];
    __shared__ unsigned int   raw[MAX_BUCKET_EDGES];
    __shared__ unsigned int   srcs[MAX_BUCKET_EDGES];
    __shared__ int cntArr[NKEY];
    __shared__ int nodeOff[NKEY + 1];
    __shared__ int curN[NKEY];
    __shared__ int wsum[8];
    const int t    = threadIdx.x;
    const int b    = blockIdx.x;
    const int lane = t & 63;
    const int wid  = t >> 6;

    // phase A: per-chunk fragment start/len (coalesced u16 row reads) + scan
    int st = 0, len = 0;
    if (t < NCH) {
        st  = __builtin_nontemporal_load(tableT + (size_t)b * NCHP + t);
        len = (int)__builtin_nontemporal_load(tableT + (size_t)(b + 1) * NCHP + t) - st;
    }
    startA[t] = st;
    lenA[t]   = (unsigned short)len;
    cntArr[t] = 0;                               // all 512 keys
    int s = wscan_incl(len);
    if (lane == 63) wsum[wid] = s;               // 8 wave totals
    __syncthreads();
    if (t < 8) {
        int w  = wsum[t];
        wsum[t] = wscan_incl(w);
    }
    __syncthreads();
    int incl = s + (wid ? wsum[wid - 1] : 0);
    destB[t] = incl - len;
    int cntTot = wsum[7];                        // bucket edge total
    if (cntTot > MAX_BUCKET_EDGES) cntTot = MAX_BUCKET_EDGES;
    __syncthreads();                             // destB visible to all waves

    // phase B: gather fragments into raw[] (8 lanes/fragment, nontemporal)
    {
        const int cj = t >> 3;                   // 64 fragments per sweep
        const int jj = t & 7;
        for (int c0 = 0; c0 < NCH; c0 += 64) {
            int c = c0 + cj;
            if (c < NCH) {
                int l = lenA[c], s0 = startA[c], db = destB[c];
                const unsigned int* p = bins + (size_t)c * CH + s0;
                for (int q = jj; q < l; q += 8)
                    raw[db + q] = __builtin_nontemporal_load(p + q);
            }
        }
    }
    __syncthreads();

    // phase C: 512-bin CSR keyed by (local_node, src_range)
    for (int i = t; i < cntTot; i += 512) {
        unsigned int p = raw[i];
        int key = ((p >> SRC_BITS) << 2) | ((p & SRC_MASK) / RANGE_SZ);
        atomicAdd(&cntArr[key], 1);
    }
    __syncthreads();
    int v2 = cntArr[t];
    int s2 = wscan_incl(v2);
    if (lane == 63) wsum[wid] = s2;
    __syncthreads();
    if (t < 8) {
        int w  = wsum[t];
        wsum[t] = wscan_incl(w);
    }
    __syncthreads();
    int excl = s2 + (wid ? wsum[wid - 1] : 0) - v2;
    nodeOff[t] = excl;
    curN[t]    = excl;
    if (t == 0) nodeOff[NKEY] = cntTot;
    __syncthreads();
    for (int i = t; i < cntTot; i += 512) {
        unsigned int p = raw[i];
        int key = ((p >> SRC_BITS) << 2) | ((p & SRC_MASK) / RANGE_SZ);
        int pos = atomicAdd(&curN[key], 1);
        srcs[pos] = p & SRC_MASK;
    }
    __syncthreads();

    // phase D: range-sliced gather-sum, persistent accumulators
    if (BF) {
        const int f0  = (t & 7) << 3;            // 16 B (8 bf16) per lane
        const int sub = t >> 3;                  // node slot 0..63
        float a0=0,a1=0,a2=0,a3=0,a4=0,a5=0,a6=0,a7=0;   // node sub
        float b0=0,b1=0,b2=0,b3=0,b4=0,b5=0,b6=0,b7=0;   // node 64+sub
        for (int r = 0; r < NR; ++r) {
            {   // g = 0
                int idx = (sub << 2) | r;
                int k = nodeOff[idx], end = nodeOff[idx + 1];
                for (; k + 1 < end; k += 2) {
                    const uint4 u0 = *reinterpret_cast<const uint4*>(
                        xb + (size_t)srcs[k] * D_FEAT + f0);
                    const uint4 u1 = *reinterpret_cast<const uint4*>(
                        xb + (size_t)srcs[k + 1] * D_FEAT + f0);
                    a0 += bflo(u0.x) + bflo(u1.x);
                    a1 += bfhi(u0.x) + bfhi(u1.x);
                    a2 += bflo(u0.y) + bflo(u1.y);
                    a3 += bfhi(u0.y) + bfhi(u1.y);
                    a4 += bflo(u0.z) + bflo(u1.z);
                    a5 += bfhi(u0.z) + bfhi(u1.z);
                    a6 += bflo(u0.w) + bflo(u1.w);
                    a7 += bfhi(u0.w) + bfhi(u1.w);
                }
                if (k < end) {
                    const uint4 u = *reinterpret_cast<const uint4*>(
                        xb + (size_t)srcs[k] * D_FEAT + f0);
                    a0 += bflo(u.x); a1 += bfhi(u.x);
                    a2 += bflo(u.y); a3 += bfhi(u.y);
                    a4 += bflo(u.z); a5 += bfhi(u.z);
                    a6 += bflo(u.w); a7 += bfhi(u.w);
                }
            }
            {   // g = 1
                int idx = ((64 + sub) << 2) | r;
                int k = nodeOff[idx], end = nodeOff[idx + 1];
                for (; k + 1 < end; k += 2) {
                    const uint4 u0 = *reinterpret_cast<const uint4*>(
                        xb + (size_t)srcs[k] * D_FEAT + f0);
                    const uint4 u1 = *reinterpret_cast<const uint4*>(
                        xb + (size_t)srcs[k + 1] * D_FEAT + f0);
                    b0 += bflo(u0.x) + bflo(u1.x);
                    b1 += bfhi(u0.x) + bfhi(u1.x);
                    b2 += bflo(u0.y) + bflo(u1.y);
                    b3 += bfhi(u0.y) + bfhi(u1.y);
                    b4 += bflo(u0.z) + bflo(u1.z);
                    b5 += bfhi(u0.z) + bfhi(u1.z);
                    b6 += bflo(u0.w) + bflo(u1.w);
                    b7 += bfhi(u0.w) + bfhi(u1.w);
                }
                if (k < end) {
                    const uint4 u = *reinterpret_cast<const uint4*>(
                        xb + (size_t)srcs[k] * D_FEAT + f0);
                    b0 += bflo(u.x); b1 += bfhi(u.x);
                    b2 += bflo(u.y); b3 += bfhi(u.y);
                    b4 += bflo(u.z); b5 += bfhi(u.z);
                    b6 += bflo(u.w); b7 += bfhi(u.w);
                }
            }
            __syncthreads();                     // keep ranges in lockstep
        }
        {
            int node = b * NODES_PER_B + sub;
            if (node < N_NODES) {
                float* op = out + (size_t)node * D_FEAT + f0;
                f32x4 w0 = {a0, a1, a2, a3};
                f32x4 w1 = {a4, a5, a6, a7};
                __builtin_nontemporal_store(w0, reinterpret_cast<f32x4*>(op));
                __builtin_nontemporal_store(w1, reinterpret_cast<f32x4*>(op + 4));
            }
            node = b * NODES_PER_B + 64 + sub;
            if (node < N_NODES) {
                float* op = out + (size_t)node * D_FEAT + f0;
                f32x4 w0 = {b0, b1, b2, b3};
                f32x4 w1 = {b4, b5, b6, b7};
                __builtin_nontemporal_store(w0, reinterpret_cast<f32x4*>(op));
                __builtin_nontemporal_store(w1, reinterpret_cast<f32x4*>(op + 4));
            }
        }
    } else {
        // fp32: 16 lanes/node, float4 per lane (x in original layout)
        int lane4 = (t & 15) << 2;
        for (int g = 0; g < NODES_PER_B / 32; ++g) {       // 4 passes
            int local = g * 32 + (t >> 4);
            int node  = b * NODES_PER_B + local;
            int beg = nodeOff[local << 2], end = nodeOff[(local << 2) + 4];
            float4 acc = make_float4(0.f, 0.f, 0.f, 0.f);
            int k = beg;
            for (; k + 1 < end; k += 2) {
                unsigned int i0 = srcs[k], i1 = srcs[k + 1];
                const float4 a = *reinterpret_cast<const float4*>(x + (size_t)i0 * D_FEAT + lane4);
                const float4 c = *reinterpret_cast<const float4*>(x + (size_t)i1 * D_FEAT + lane4);
                acc.x += a.x + c.x; acc.y += a.y + c.y;
                acc.z += a.z + c.z; acc.w += a.w + c.w;
            }
            if (k < end) {
                unsigned int i0 = srcs[k];
                const float4 a = *reinterpret_cast<const float4*>(x + (size_t)i0 * D_FEAT + lane4);
                acc.x += a.x; acc.y += a.y; acc.z += a.z; acc.w += a.w;
            }
            if (node < N_NODES)
                *reinterpret_cast<float4*>(out + (size_t)node * D_FEAT + lane4) = acc;
        }
    }
}

extern "C" void kernel_launch(void* const* d_in, const int* in_sizes, int n_in,
                              void* d_out, int out_size, void* d_ws, size_t ws_size,
                              hipStream_t stream) {
    const float* x   = (const float*)d_in[1];
    const int*   ei  = (const int*)d_in[2];
    const int*   src = ei;
    const int*   dst = ei + N_EDGES;
    float*       out = (float*)d_out;

    const size_t tabBytes = (size_t)TROW * NCHP * sizeof(unsigned short); // ~400 KB
    const size_t binBytes = (size_t)N_EDGES * sizeof(unsigned int);       // 5 MB
    const size_t xbOff    = (binBytes + tabBytes + 15) & ~(size_t)15;
    const size_t needA    = xbOff + (size_t)N_NODES * D_FEAT * sizeof(unsigned short); // ~18.2 MB
    const size_t needB    = binBytes + tabBytes;                                        // ~5.4 MB

    if (ws_size >= needA) {
        unsigned int*   bins   = (unsigned int*)d_ws;
        unsigned short* tableT = (unsigned short*)((char*)d_ws + binBytes);
        unsigned short* xb     = (unsigned short*)((char*)d_ws + xbOff);
        k1_sort<true><<<NCH, 1024, 0, stream>>>(x, xb, src, dst, bins, tableT);
        k2_accum<true><<<N_BUCKETS, 512, 0, stream>>>(x, xb, bins, tableT, out);
    } else if (ws_size >= needB) {
        unsigned int*   bins   = (unsigned int*)d_ws;
        unsigned short* tableT = (unsigned short*)((char*)d_ws + binBytes);
        k1_sort<false><<<NCH, 1024, 0, stream>>>(x, nullptr, src, dst, bins, tableT);
        k2_accum<false><<<N_BUCKETS, 512, 0, stream>>>(x, nullptr, bins, tableT, out);
    } else {
        (void)hipMemsetAsync(out, 0, (size_t)out_size * sizeof(float), stream);
        const int total = N_EDGES * 16;
        lgconv_scatter<<<(total + 255) / 256, 256, 0, stream>>>(x, src, dst, out);
    }
}